// Round 4
// baseline (1861.868 us; speedup 1.0000x reference)
//
#include <hip/hip_runtime.h>
#include <math.h>

typedef _Float16 f16;
typedef unsigned int u32;
typedef __attribute__((ext_vector_type(8))) _Float16 f16x8;   // 4 VGPR operand frag
typedef __attribute__((ext_vector_type(16))) float f32x16;    // 32x32 accumulator

#define LO_SCALE 4096.0f
#define LO_INV   2.44140625e-4f   // 1/4096

// f16 scaled split: x ~= h + l*(1/4096), |err| ~ 2^-22 |x|
__device__ __forceinline__ void split2f(float x, f16 &h, f16 &l) {
    h = (f16)x;
    l = (f16)((x - (float)h) * LO_SCALE);
}
__device__ __forceinline__ f32x16 mfma32(f16x8 a, f16x8 b, f32x16 c) {
    return __builtin_amdgcn_mfma_f32_32x32x16_f16(a, b, c, 0, 0, 0);
}

// ---------- prep: W [K][N] fp32 row-major -> fragment-ordered hi/lo ----------
// out[((nt*ksteps + ks)*2 + hl)*512 + lane*8 + e]
//   n = nt*32 + (lane&31), k = ks*16 + (lane>>5)*8 + e
__global__ __launch_bounds__(256) void prep_frag(
    const float* __restrict__ W, int K, int N, int ksteps, int ntiles,
    f16* __restrict__ out)
{
    int total = ntiles * ksteps * 512;
    for (int i = blockIdx.x * blockDim.x + threadIdx.x; i < total;
         i += gridDim.x * blockDim.x) {
        int le = i & 511;
        int ks = (i >> 9) % ksteps;
        int nt = i / (512 * ksteps);
        int lane = le >> 3, e = le & 7;
        int n = nt * 32 + (lane & 31);
        int k = ks * 16 + (lane >> 5) * 8 + e;
        float w = (k < K && n < N) ? W[k * N + n] : 0.f;
        f16 h, l; split2f(w, h, l);
        size_t base = ((size_t)(nt * ksteps + ks) * 2) * 512 + le;
        out[base] = h;
        out[base + 512] = l;
    }
}

// ---------- kernel 1: VAE decoder (21 -> 750 -> 750 -> 3, tanh), M=64 ----------
#define DEC_T 768     // 12 waves
#define DEC_LDH 392   // f16 pitch: 784 B = 49 16B-chunks (odd) -> conflict-free b128
#define XPITCH 40     // f16 pitch: 80 B = 5 chunks

__global__ __launch_bounds__(768, 3) void dec_kernel(
    const float* __restrict__ states, const float* __restrict__ noise,
    const f16* __restrict__ w1f, const float* __restrict__ b1,
    const f16* __restrict__ w2f, const float* __restrict__ b2,
    const float* __restrict__ w3, const float* __restrict__ b3,
    float* __restrict__ adec)
{
    __shared__ __align__(16) f16 Xh[64 * XPITCH];
    __shared__ __align__(16) f16 Xl[64 * XPITCH];
    __shared__ __align__(16) f16 H1h[64 * DEC_LDH];
    __shared__ __align__(16) f16 H1l[64 * DEC_LDH];
    __shared__ float ow[12][64][3];

    const int tid = threadIdx.x;
    const int lane = tid & 63;
    const int wid = tid >> 6;       // 0..11
    const int l31 = lane & 31;
    const int l5  = lane >> 5;
    const int rowblk = blockIdx.x * 64;

    // X = [state(11) | clip(noise)(10) | 0...], pre-split into f16 hi/lo
    for (int idx = tid; idx < 64 * 32; idx += DEC_T) {
        int r = idx >> 5, c = idx & 31;
        int g = rowblk + r;
        float v = 0.f;
        if (c < 11) v = states[(g / 10) * 11 + c];
        else if (c < 21) {
            float z = noise[g * 10 + (c - 11)];
            v = fminf(fmaxf(z, -0.5f), 0.5f);
        }
        f16 hh, ll; split2f(v, hh, ll);
        Xh[r * XPITCH + c] = hh;
        Xl[r * XPITCH + c] = ll;
    }

    // persistent phase-2 accumulators: 2 n-tiles x 2 m-tiles x (main, cross)
    f32x16 am[2][2], ac[2][2];
    #pragma unroll
    for (int t = 0; t < 2; ++t)
        #pragma unroll
        for (int m = 0; m < 2; ++m)
            #pragma unroll
            for (int r = 0; r < 16; ++r) { am[t][m][r] = 0.f; ac[t][m][r] = 0.f; }

    __syncthreads();

    // two K-halves: phase1 fills H1 cols [h*384,(h+1)*384), phase2 consumes
    for (int h = 0; h < 2; ++h) {
        // ---- phase 1: 12 tiles per half, 1 per wave; two passes (pm, then pc)
        {
            const int nt = h * 12 + wid;
            const int col = nt * 32 + l31;
            const float bias = (col < 750) ? b1[col] : 0.f;
            #pragma unroll
            for (int m = 0; m < 2; ++m) {
                f32x16 pm;
                #pragma unroll
                for (int r = 0; r < 16; ++r) pm[r] = 0.f;
                #pragma unroll
                for (int ks = 0; ks < 2; ++ks) {
                    const f16x8 xh = *(const f16x8*)&Xh[(m * 32 + l31) * XPITCH + ks * 16 + l5 * 8];
                    size_t base = ((size_t)(nt * 2 + ks) * 2) * 512 + lane * 8;
                    const f16x8 bh = *(const f16x8*)&w1f[base];
                    pm = mfma32(xh, bh, pm);
                }
                f32x16 pc;
                #pragma unroll
                for (int r = 0; r < 16; ++r) pc[r] = 0.f;
                #pragma unroll
                for (int ks = 0; ks < 2; ++ks) {
                    const f16x8 xh = *(const f16x8*)&Xh[(m * 32 + l31) * XPITCH + ks * 16 + l5 * 8];
                    const f16x8 xl = *(const f16x8*)&Xl[(m * 32 + l31) * XPITCH + ks * 16 + l5 * 8];
                    size_t base = ((size_t)(nt * 2 + ks) * 2) * 512 + lane * 8;
                    const f16x8 bh = *(const f16x8*)&w1f[base];
                    const f16x8 bl = *(const f16x8*)&w1f[base + 512];
                    pc = mfma32(xl, bh, pc);
                    pc = mfma32(xh, bl, pc);
                }
                const int lc = wid * 32 + l31;   // column within this K-half buffer
                #pragma unroll
                for (int r = 0; r < 16; ++r) {
                    int row = m * 32 + (r & 3) + 8 * (r >> 2) + 4 * l5;
                    float v = fmaxf(fmaf(pc[r], LO_INV, pm[r]) + bias, 0.f);
                    f16 hh, ll; split2f(v, hh, ll);
                    H1h[row * DEC_LDH + lc] = hh;
                    H1l[row * DEC_LDH + lc] = ll;
                }
            }
        }
        __syncthreads();

        // ---- phase 2: wave owns n-tiles {2*wid, 2*wid+1}; K-half = 24 ksteps
        for (int ks = 0; ks < 24; ++ks) {
            const int ksg = h * 24 + ks;
            const f16x8 ah0 = *(const f16x8*)&H1h[l31 * DEC_LDH + ks * 16 + l5 * 8];
            const f16x8 al0 = *(const f16x8*)&H1l[l31 * DEC_LDH + ks * 16 + l5 * 8];
            const f16x8 ah1 = *(const f16x8*)&H1h[(32 + l31) * DEC_LDH + ks * 16 + l5 * 8];
            const f16x8 al1 = *(const f16x8*)&H1l[(32 + l31) * DEC_LDH + ks * 16 + l5 * 8];
            #pragma unroll
            for (int t = 0; t < 2; ++t) {
                const int nt = wid * 2 + t;
                size_t base = ((size_t)(nt * 48 + ksg) * 2) * 512 + lane * 8;
                const f16x8 bh = *(const f16x8*)&w2f[base];
                const f16x8 bl = *(const f16x8*)&w2f[base + 512];
                am[t][0] = mfma32(ah0, bh, am[t][0]);
                ac[t][0] = mfma32(al0, bh, ac[t][0]);
                ac[t][0] = mfma32(ah0, bl, ac[t][0]);
                am[t][1] = mfma32(ah1, bh, am[t][1]);
                ac[t][1] = mfma32(al1, bh, ac[t][1]);
                ac[t][1] = mfma32(ah1, bl, ac[t][1]);
            }
        }
        __syncthreads();
    }

    // fold cross terms into main (frees ac)
    #pragma unroll
    for (int t = 0; t < 2; ++t)
        #pragma unroll
        for (int m = 0; m < 2; ++m)
            #pragma unroll
            for (int r = 0; r < 16; ++r)
                am[t][m][r] = fmaf(ac[t][m][r], LO_INV, am[t][m][r]);

    // phase 3: A = tanh(relu(H2)*W3 + b3), per-lane dot + shuffle reduce
    #pragma unroll
    for (int j = 0; j < 3; ++j) {
        float p0[16], p1[16];
        #pragma unroll
        for (int r = 0; r < 16; ++r) { p0[r] = 0.f; p1[r] = 0.f; }
        #pragma unroll
        for (int t = 0; t < 2; ++t) {
            int col = (wid * 2 + t) * 32 + l31;
            float bias = 0.f, wv = 0.f;
            if (col < 750) { bias = b2[col]; wv = w3[col * 3 + j]; }
            #pragma unroll
            for (int r = 0; r < 16; ++r) {
                p0[r] += fmaxf(am[t][0][r] + bias, 0.f) * wv;
                p1[r] += fmaxf(am[t][1][r] + bias, 0.f) * wv;
            }
        }
        #pragma unroll
        for (int msk = 1; msk < 32; msk <<= 1) {
            #pragma unroll
            for (int r = 0; r < 16; ++r) {
                p0[r] += __shfl_xor(p0[r], msk);
                p1[r] += __shfl_xor(p1[r], msk);
            }
        }
        if (l31 == 0) {
            #pragma unroll
            for (int r = 0; r < 16; ++r) {
                int row = (r & 3) + 8 * (r >> 2) + 4 * l5;
                ow[wid][row][j] = p0[r];
                ow[wid][32 + row][j] = p1[r];
            }
        }
    }
    __syncthreads();
    if (tid < 192) {
        int row = tid / 3, j = tid - row * 3;
        float s = 0.f;
        #pragma unroll
        for (int w = 0; w < 12; ++w) s += ow[w][row][j];
        adec[(rowblk + row) * 3 + j] = tanhf(s + b3[j]);
    }
}

// ---------- kernel 2: actor + twin critics, M=64 ----------
#define AQ_T 640
#define AQ_LDH 456    // 912 B = 57 chunks (odd) -> conflict-free

template<int NJ>
__device__ __forceinline__ void mlp_net2(
    const f16* __restrict__ w1f, const float* __restrict__ b1,
    const f16* __restrict__ w2f, const float* __restrict__ b2,
    const float* __restrict__ w3,
    const f16* Xh, const f16* Xl, f16* H1h, f16* H1l, float (*ow)[64][3], int tid)
{
    const int lane = tid & 63;
    const int wid = tid >> 6;       // 0..9
    const int l31 = lane & 31;
    const int l5  = lane >> 5;

    // phase 1: 14 tiles (448 cols), K=32
    for (int rep = 0; rep < 2; ++rep) {
        if (rep == 1 && wid >= 4) break;
        int t = (rep == 0) ? wid : 10 + wid;
        #pragma unroll
        for (int m = 0; m < 2; ++m) {
            f32x16 pm, pc;
            #pragma unroll
            for (int r = 0; r < 16; ++r) { pm[r] = 0.f; pc[r] = 0.f; }
            #pragma unroll
            for (int ks = 0; ks < 2; ++ks) {
                const f16x8 xh = *(const f16x8*)&Xh[(m * 32 + l31) * XPITCH + ks * 16 + l5 * 8];
                const f16x8 xl = *(const f16x8*)&Xl[(m * 32 + l31) * XPITCH + ks * 16 + l5 * 8];
                size_t base = ((size_t)(t * 2 + ks) * 2) * 512 + lane * 8;
                const f16x8 bh = *(const f16x8*)&w1f[base];
                const f16x8 bl = *(const f16x8*)&w1f[base + 512];
                pm = mfma32(xh, bh, pm);
                pc = mfma32(xl, bh, pc);
                pc = mfma32(xh, bl, pc);
            }
            int col = t * 32 + l31;
            float bias = (col < 400) ? b1[col] : 0.f;
            #pragma unroll
            for (int r = 0; r < 16; ++r) {
                int row = m * 32 + (r & 3) + 8 * (r >> 2) + 4 * l5;
                float v = fmaxf(fmaf(pc[r], LO_INV, pm[r]) + bias, 0.f);
                f16 hh, ll; split2f(v, hh, ll);
                H1h[row * AQ_LDH + col] = hh;
                H1l[row * AQ_LDH + col] = ll;
            }
        }
    }
    __syncthreads();

    // phase 2: wave owns n-tile wid (0..9), K=448 (28 ksteps)
    f32x16 am0, ac0, am1, ac1;
    #pragma unroll
    for (int r = 0; r < 16; ++r) { am0[r] = 0.f; ac0[r] = 0.f; am1[r] = 0.f; ac1[r] = 0.f; }
    for (int ks = 0; ks < 28; ++ks) {
        const f16x8 ah0 = *(const f16x8*)&H1h[l31 * AQ_LDH + ks * 16 + l5 * 8];
        const f16x8 al0 = *(const f16x8*)&H1l[l31 * AQ_LDH + ks * 16 + l5 * 8];
        const f16x8 ah1 = *(const f16x8*)&H1h[(32 + l31) * AQ_LDH + ks * 16 + l5 * 8];
        const f16x8 al1 = *(const f16x8*)&H1l[(32 + l31) * AQ_LDH + ks * 16 + l5 * 8];
        size_t base = ((size_t)(wid * 28 + ks) * 2) * 512 + lane * 8;
        const f16x8 bh = *(const f16x8*)&w2f[base];
        const f16x8 bl = *(const f16x8*)&w2f[base + 512];
        am0 = mfma32(ah0, bh, am0);
        ac0 = mfma32(al0, bh, ac0);
        ac0 = mfma32(ah0, bl, ac0);
        am1 = mfma32(ah1, bh, am1);
        ac1 = mfma32(al1, bh, ac1);
        ac1 = mfma32(ah1, bl, ac1);
    }
    #pragma unroll
    for (int r = 0; r < 16; ++r) {
        am0[r] = fmaf(ac0[r], LO_INV, am0[r]);
        am1[r] = fmaf(ac1[r], LO_INV, am1[r]);
    }

    // phase 3
    int col = wid * 32 + l31;
    #pragma unroll
    for (int j = 0; j < NJ; ++j) {
        float p0[16], p1[16];
        #pragma unroll
        for (int r = 0; r < 16; ++r) { p0[r] = 0.f; p1[r] = 0.f; }
        float bias = 0.f, wv = 0.f;
        if (col < 300) { bias = b2[col]; wv = w3[col * NJ + j]; }
        #pragma unroll
        for (int r = 0; r < 16; ++r) {
            p0[r] += fmaxf(am0[r] + bias, 0.f) * wv;
            p1[r] += fmaxf(am1[r] + bias, 0.f) * wv;
        }
        #pragma unroll
        for (int msk = 1; msk < 32; msk <<= 1) {
            #pragma unroll
            for (int r = 0; r < 16; ++r) {
                p0[r] += __shfl_xor(p0[r], msk);
                p1[r] += __shfl_xor(p1[r], msk);
            }
        }
        if (l31 == 0) {
            #pragma unroll
            for (int r = 0; r < 16; ++r) {
                int row = (r & 3) + 8 * (r >> 2) + 4 * l5;
                ow[wid][row][j] = p0[r];
                ow[wid][32 + row][j] = p1[r];
            }
        }
    }
    // caller syncs before reading ow
}

__global__ __launch_bounds__(640, 3) void aq_kernel(
    const float* __restrict__ states, const float* __restrict__ adec,
    const f16* __restrict__ aw1f, const float* __restrict__ ab1,
    const f16* __restrict__ aw2f, const float* __restrict__ ab2,
    const float* __restrict__ aw3, const float* __restrict__ ab3,
    const f16* __restrict__ c1w1f, const float* __restrict__ c1b1,
    const f16* __restrict__ c1w2f, const float* __restrict__ c1b2,
    const float* __restrict__ c1w3, const float* __restrict__ c1b3,
    const f16* __restrict__ c2w1f, const float* __restrict__ c2b1,
    const f16* __restrict__ c2w2f, const float* __restrict__ c2b2,
    const float* __restrict__ c2w3, const float* __restrict__ c2b3,
    float* __restrict__ actions, float* __restrict__ qmin)
{
    __shared__ __align__(16) f16 Xh[64 * XPITCH];
    __shared__ __align__(16) f16 Xl[64 * XPITCH];
    __shared__ __align__(16) f16 H1h[64 * AQ_LDH];
    __shared__ __align__(16) f16 H1l[64 * AQ_LDH];
    __shared__ float ow[10][64][3];
    __shared__ float q1v[64];

    const int tid = threadIdx.x;
    const int rowblk = blockIdx.x * 64;

    // X = [state(11) | a_dec(3) | 0...], pre-split
    for (int idx = tid; idx < 64 * 32; idx += AQ_T) {
        int r = idx >> 5, c = idx & 31;
        int g = rowblk + r;
        float v = 0.f;
        if (c < 11) v = states[(g / 10) * 11 + c];
        else if (c < 14) v = adec[g * 3 + (c - 11)];
        f16 hh, ll; split2f(v, hh, ll);
        Xh[r * XPITCH + c] = hh;
        Xl[r * XPITCH + c] = ll;
    }
    __syncthreads();

    // actor
    mlp_net2<3>(aw1f, ab1, aw2f, ab2, aw3, Xh, Xl, H1h, H1l, ow, tid);
    __syncthreads();
    if (tid < 192) {
        int row = tid / 3, j = tid - row * 3;
        float s = 0.f;
        #pragma unroll
        for (int w = 0; w < 10; ++w) s += ow[w][row][j];
        float da = tanhf(s + ab3[j]);
        float ap = (float)Xh[row * XPITCH + 11 + j]
                 + (float)Xl[row * XPITCH + 11 + j] * LO_INV;
        float act = fminf(fmaxf(0.05f * da + ap, -1.f), 1.f);
        actions[(rowblk + row) * 3 + j] = act;
        f16 hh, ll; split2f(act, hh, ll);
        Xh[row * XPITCH + 11 + j] = hh;
        Xl[row * XPITCH + 11 + j] = ll;
    }
    __syncthreads();

    // q1
    mlp_net2<1>(c1w1f, c1b1, c1w2f, c1b2, c1w3, Xh, Xl, H1h, H1l, ow, tid);
    __syncthreads();
    if (tid < 64) {
        float s = 0.f;
        #pragma unroll
        for (int w = 0; w < 10; ++w) s += ow[w][tid][0];
        q1v[tid] = s + c1b3[0];
    }
    __syncthreads();

    // q2 + min
    mlp_net2<1>(c2w1f, c2b1, c2w2f, c2b2, c2w3, Xh, Xl, H1h, H1l, ow, tid);
    __syncthreads();
    if (tid < 64) {
        float s = 0.f;
        #pragma unroll
        for (int w = 0; w < 10; ++w) s += ow[w][tid][0];
        qmin[rowblk + tid] = fminf(q1v[tid], s + c2b3[0]);
    }
}

// ---------- kernel 3: per-state argmax (first max) + gather ----------
__global__ __launch_bounds__(256) void select_kernel(
    const float* __restrict__ qmin, const float* __restrict__ actions,
    float* __restrict__ out)
{
    int s = blockIdx.x * blockDim.x + threadIdx.x;
    if (s >= 16384) return;
    const float* q = qmin + s * 10;
    int best = 0;
    float bq = q[0];
    #pragma unroll
    for (int i = 1; i < 10; ++i) {
        float v = q[i];
        if (v > bq) { bq = v; best = i; }
    }
    const float* a = actions + (size_t)(s * 10 + best) * 3;
    out[s * 3 + 0] = a[0];
    out[s * 3 + 1] = a[1];
    out[s * 3 + 2] = a[2];
}

extern "C" void kernel_launch(void* const* d_in, const int* in_sizes, int n_in,
                              void* d_out, int out_size, void* d_ws, size_t ws_size,
                              hipStream_t stream)
{
    const float* states = (const float*)d_in[0];
    const float* noise  = (const float*)d_in[1];
    const float* dec_w1 = (const float*)d_in[2];
    const float* dec_b1 = (const float*)d_in[3];
    const float* dec_w2 = (const float*)d_in[4];
    const float* dec_b2 = (const float*)d_in[5];
    const float* dec_w3 = (const float*)d_in[6];
    const float* dec_b3 = (const float*)d_in[7];
    const float* act_w1 = (const float*)d_in[8];
    const float* act_b1 = (const float*)d_in[9];
    const float* act_w2 = (const float*)d_in[10];
    const float* act_b2 = (const float*)d_in[11];
    const float* act_w3 = (const float*)d_in[12];
    const float* act_b3 = (const float*)d_in[13];
    const float* q1_w1 = (const float*)d_in[14];
    const float* q1_b1 = (const float*)d_in[15];
    const float* q1_w2 = (const float*)d_in[16];
    const float* q1_b2 = (const float*)d_in[17];
    const float* q1_w3 = (const float*)d_in[18];
    const float* q1_b3 = (const float*)d_in[19];
    const float* q2_w1 = (const float*)d_in[20];
    const float* q2_b1 = (const float*)d_in[21];
    const float* q2_w2 = (const float*)d_in[22];
    const float* q2_b2 = (const float*)d_in[23];
    const float* q2_w3 = (const float*)d_in[24];
    const float* q2_b3 = (const float*)d_in[25];

    char* base = (char*)d_ws;
    size_t off = 0;
    auto carve = [&](size_t bytes) -> void* {
        void* p = base + off;
        off = (off + bytes + 255) & ~(size_t)255;
        return p;
    };
    f16* w1df = (f16*)carve((size_t)24 * 2 * 1024 * 2);
    f16* w2df = (f16*)carve((size_t)24 * 48 * 1024 * 2);
    f16* aw1f = (f16*)carve((size_t)14 * 2 * 1024 * 2);
    f16* aw2f = (f16*)carve((size_t)10 * 28 * 1024 * 2);
    f16* c1w1f = (f16*)carve((size_t)14 * 2 * 1024 * 2);
    f16* c1w2f = (f16*)carve((size_t)10 * 28 * 1024 * 2);
    f16* c2w1f = (f16*)carve((size_t)14 * 2 * 1024 * 2);
    f16* c2w2f = (f16*)carve((size_t)10 * 28 * 1024 * 2);
    float* adec = (float*)carve((size_t)163840 * 3 * 4);
    float* acts = (float*)carve((size_t)163840 * 3 * 4);
    float* qmn  = (float*)carve((size_t)163840 * 4);
    if (off > ws_size) return;  // workspace too small: bail

    auto prep = [&](const float* W, int K, int N, int ksteps, int ntiles, f16* out) {
        int total = ntiles * ksteps * 512;
        int grid = (total + 255) / 256;
        if (grid > 2048) grid = 2048;
        prep_frag<<<grid, 256, 0, stream>>>(W, K, N, ksteps, ntiles, out);
    };
    prep(dec_w1, 21, 750, 2, 24, w1df);
    prep(dec_w2, 750, 750, 48, 24, w2df);
    prep(act_w1, 14, 400, 2, 14, aw1f);
    prep(act_w2, 400, 300, 28, 10, aw2f);
    prep(q1_w1, 14, 400, 2, 14, c1w1f);
    prep(q1_w2, 400, 300, 28, 10, c1w2f);
    prep(q2_w1, 14, 400, 2, 14, c2w1f);
    prep(q2_w2, 400, 300, 28, 10, c2w2f);

    dec_kernel<<<2560, DEC_T, 0, stream>>>(states, noise,
        w1df, dec_b1, w2df, dec_b2, dec_w3, dec_b3, adec);

    aq_kernel<<<2560, AQ_T, 0, stream>>>(states, adec,
        aw1f, act_b1, aw2f, act_b2, act_w3, act_b3,
        c1w1f, q1_b1, c1w2f, q1_b2, q1_w3, q1_b3,
        c2w1f, q2_b1, c2w2f, q2_b2, q2_w3, q2_b3,
        acts, qmn);

    select_kernel<<<64, 256, 0, stream>>>(qmn, acts, (float*)d_out);
}

// Round 5
// 1323.218 us; speedup vs baseline: 1.4071x; 1.4071x over previous
//
#include <hip/hip_runtime.h>
#include <math.h>

typedef _Float16 f16;
typedef unsigned int u32;
typedef __attribute__((ext_vector_type(8))) _Float16 f16x8;   // 4 VGPR operand frag
typedef __attribute__((ext_vector_type(16))) float f32x16;    // 32x32 accumulator

#define LO_SCALE 4096.0f
#define LO_INV   2.44140625e-4f   // 1/4096

// f16 scaled split: x ~= h + l*(1/4096), |err| ~ 2^-22 |x|
__device__ __forceinline__ void split2f(float x, f16 &h, f16 &l) {
    h = (f16)x;
    l = (f16)((x - (float)h) * LO_SCALE);
}
__device__ __forceinline__ f32x16 mfma32(f16x8 a, f16x8 b, f32x16 c) {
    return __builtin_amdgcn_mfma_f32_32x32x16_f16(a, b, c, 0, 0, 0);
}

// ---------- prep: W [K][N] fp32 row-major -> fragment-ordered hi/lo ----------
// out[((nt*ksteps + ks)*2 + hl)*512 + lane*8 + e]
//   n = nt*32 + (lane&31), k = ks*16 + (lane>>5)*8 + e
__global__ __launch_bounds__(256) void prep_frag(
    const float* __restrict__ W, int K, int N, int ksteps, int ntiles,
    f16* __restrict__ out)
{
    int total = ntiles * ksteps * 512;
    for (int i = blockIdx.x * blockDim.x + threadIdx.x; i < total;
         i += gridDim.x * blockDim.x) {
        int le = i & 511;
        int ks = (i >> 9) % ksteps;
        int nt = i / (512 * ksteps);
        int lane = le >> 3, e = le & 7;
        int n = nt * 32 + (lane & 31);
        int k = ks * 16 + (lane >> 5) * 8 + e;
        float w = (k < K && n < N) ? W[k * N + n] : 0.f;
        f16 h, l; split2f(w, h, l);
        size_t base = ((size_t)(nt * ksteps + ks) * 2) * 512 + le;
        out[base] = h;
        out[base + 512] = l;
    }
}

// ---------- kernel 1: VAE decoder (21 -> 750 -> 750 -> 3, tanh), M=64 ----------
#define DEC_T 512     // 8 waves; 1 block/CU (LDS) -> exactly 2 waves/SIMD
#define DEC_LDH 392   // f16 pitch: 784 B = 49 16B-chunks (odd) -> conflict-free b128
#define XPITCH 40     // f16 pitch: 80 B = 5 chunks

// waves_per_eu(2,2): LDS caps us at 1 block/CU = 2 waves/SIMD anyway; pin it so
// the allocator gets the full 256-VGPR budget (round-4 lesson: heuristic chose
// 84 regs for a 6-wave target and spilled 2.5 GB of accumulators per dispatch).
__attribute__((amdgpu_waves_per_eu(2, 2)))
__global__ void __launch_bounds__(512) dec_kernel(
    const float* __restrict__ states, const float* __restrict__ noise,
    const f16* __restrict__ w1f, const float* __restrict__ b1,
    const f16* __restrict__ w2f, const float* __restrict__ b2,
    const float* __restrict__ w3, const float* __restrict__ b3,
    float* __restrict__ adec)
{
    __shared__ __align__(16) f16 Xh[64 * XPITCH];
    __shared__ __align__(16) f16 Xl[64 * XPITCH];
    __shared__ __align__(16) f16 H1h[64 * DEC_LDH];
    __shared__ __align__(16) f16 H1l[64 * DEC_LDH];
    __shared__ float ow[8][64][3];

    const int tid = threadIdx.x;
    const int lane = tid & 63;
    const int wid = tid >> 6;       // 0..7
    const int l31 = lane & 31;
    const int l5  = lane >> 5;
    const int rowblk = blockIdx.x * 64;

    // X = [state(11) | clip(noise)(10) | 0...], pre-split into f16 hi/lo
    for (int idx = tid; idx < 64 * 32; idx += DEC_T) {
        int r = idx >> 5, c = idx & 31;
        int g = rowblk + r;
        float v = 0.f;
        if (c < 11) v = states[(g / 10) * 11 + c];
        else if (c < 21) {
            float z = noise[g * 10 + (c - 11)];
            v = fminf(fmaxf(z, -0.5f), 0.5f);
        }
        f16 hh, ll; split2f(v, hh, ll);
        Xh[r * XPITCH + c] = hh;
        Xl[r * XPITCH + c] = ll;
    }
    __syncthreads();

    // phase 1 for K-half h: fill H1 cols [h*384,(h+1)*384); 12 tiles, two-pass
    auto phase1 = [&](int h) {
        for (int rep = 0; rep < 2; ++rep) {
            if (rep == 1 && wid >= 4) break;
            const int tl = (rep == 0) ? wid : 8 + wid;
            const int nt = h * 12 + tl;
            const int col = nt * 32 + l31;
            const float bias = (col < 750) ? b1[col] : 0.f;
            const int lc = tl * 32 + l31;    // column within this K-half buffer
            #pragma unroll
            for (int m = 0; m < 2; ++m) {
                f32x16 pm;
                #pragma unroll
                for (int r = 0; r < 16; ++r) pm[r] = 0.f;
                #pragma unroll
                for (int ks = 0; ks < 2; ++ks) {
                    const f16x8 xh = *(const f16x8*)&Xh[(m * 32 + l31) * XPITCH + ks * 16 + l5 * 8];
                    size_t base = ((size_t)(nt * 2 + ks) * 2) * 512 + lane * 8;
                    const f16x8 bh = *(const f16x8*)&w1f[base];
                    pm = mfma32(xh, bh, pm);
                }
                f32x16 pc;
                #pragma unroll
                for (int r = 0; r < 16; ++r) pc[r] = 0.f;
                #pragma unroll
                for (int ks = 0; ks < 2; ++ks) {
                    const f16x8 xh = *(const f16x8*)&Xh[(m * 32 + l31) * XPITCH + ks * 16 + l5 * 8];
                    const f16x8 xl = *(const f16x8*)&Xl[(m * 32 + l31) * XPITCH + ks * 16 + l5 * 8];
                    size_t base = ((size_t)(nt * 2 + ks) * 2) * 512 + lane * 8;
                    const f16x8 bh = *(const f16x8*)&w1f[base];
                    const f16x8 bl = *(const f16x8*)&w1f[base + 512];
                    pc = mfma32(xl, bh, pc);
                    pc = mfma32(xh, bl, pc);
                }
                #pragma unroll
                for (int r = 0; r < 16; ++r) {
                    int row = m * 32 + (r & 3) + 8 * (r >> 2) + 4 * l5;
                    float v = fmaxf(fmaf(pc[r], LO_INV, pm[r]) + bias, 0.f);
                    f16 hh, ll; split2f(v, hh, ll);
                    H1h[row * DEC_LDH + lc] = hh;
                    H1l[row * DEC_LDH + lc] = ll;
                }
            }
        }
    };

    // ---- phase 1 (h=0) runs BEFORE accumulators go live (register pressure)
    phase1(0);
    __syncthreads();

    // persistent phase-2 accumulators: 3 n-tiles x 2 m-tiles x (main, cross)
    f32x16 am[3][2], ac[3][2];
    #pragma unroll
    for (int t = 0; t < 3; ++t)
        #pragma unroll
        for (int m = 0; m < 2; ++m)
            #pragma unroll
            for (int r = 0; r < 16; ++r) { am[t][m][r] = 0.f; ac[t][m][r] = 0.f; }

    // phase 2 for K-half h: wave owns n-tiles {wid, wid+8, wid+16}
    auto phase2 = [&](int h) {
        for (int ks = 0; ks < 24; ++ks) {
            const int ksg = h * 24 + ks;
            const f16x8 ah0 = *(const f16x8*)&H1h[l31 * DEC_LDH + ks * 16 + l5 * 8];
            const f16x8 al0 = *(const f16x8*)&H1l[l31 * DEC_LDH + ks * 16 + l5 * 8];
            const f16x8 ah1 = *(const f16x8*)&H1h[(32 + l31) * DEC_LDH + ks * 16 + l5 * 8];
            const f16x8 al1 = *(const f16x8*)&H1l[(32 + l31) * DEC_LDH + ks * 16 + l5 * 8];
            #pragma unroll
            for (int t = 0; t < 3; ++t) {
                const int nt = wid + 8 * t;
                size_t base = ((size_t)(nt * 48 + ksg) * 2) * 512 + lane * 8;
                const f16x8 bh = *(const f16x8*)&w2f[base];
                const f16x8 bl = *(const f16x8*)&w2f[base + 512];
                am[t][0] = mfma32(ah0, bh, am[t][0]);
                ac[t][0] = mfma32(al0, bh, ac[t][0]);
                ac[t][0] = mfma32(ah0, bl, ac[t][0]);
                am[t][1] = mfma32(ah1, bh, am[t][1]);
                ac[t][1] = mfma32(al1, bh, ac[t][1]);
                ac[t][1] = mfma32(ah1, bl, ac[t][1]);
            }
        }
    };

    phase2(0);
    __syncthreads();
    phase1(1);
    __syncthreads();
    phase2(1);

    // fold cross terms into main (frees ac)
    #pragma unroll
    for (int t = 0; t < 3; ++t)
        #pragma unroll
        for (int m = 0; m < 2; ++m)
            #pragma unroll
            for (int r = 0; r < 16; ++r)
                am[t][m][r] = fmaf(ac[t][m][r], LO_INV, am[t][m][r]);

    // phase 3: A = tanh(relu(H2)*W3 + b3), per-lane dot + shuffle reduce
    #pragma unroll
    for (int j = 0; j < 3; ++j) {
        float p0[16], p1[16];
        #pragma unroll
        for (int r = 0; r < 16; ++r) { p0[r] = 0.f; p1[r] = 0.f; }
        #pragma unroll
        for (int t = 0; t < 3; ++t) {
            int col = (wid + 8 * t) * 32 + l31;
            float bias = 0.f, wv = 0.f;
            if (col < 750) { bias = b2[col]; wv = w3[col * 3 + j]; }
            #pragma unroll
            for (int r = 0; r < 16; ++r) {
                p0[r] += fmaxf(am[t][0][r] + bias, 0.f) * wv;
                p1[r] += fmaxf(am[t][1][r] + bias, 0.f) * wv;
            }
        }
        #pragma unroll
        for (int msk = 1; msk < 32; msk <<= 1) {
            #pragma unroll
            for (int r = 0; r < 16; ++r) {
                p0[r] += __shfl_xor(p0[r], msk);
                p1[r] += __shfl_xor(p1[r], msk);
            }
        }
        if (l31 == 0) {
            #pragma unroll
            for (int r = 0; r < 16; ++r) {
                int row = (r & 3) + 8 * (r >> 2) + 4 * l5;
                ow[wid][row][j] = p0[r];
                ow[wid][32 + row][j] = p1[r];
            }
        }
    }
    __syncthreads();
    if (tid < 192) {
        int row = tid / 3, j = tid - row * 3;
        float s = 0.f;
        #pragma unroll
        for (int w = 0; w < 8; ++w) s += ow[w][row][j];
        adec[(rowblk + row) * 3 + j] = tanhf(s + b3[j]);
    }
}

// ---------- kernel 2: actor + twin critics, M=64 ----------
#define AQ_T 640
#define AQ_LDH 456    // 912 B = 57 chunks (odd) -> conflict-free

template<int NJ>
__device__ __forceinline__ void mlp_net2(
    const f16* __restrict__ w1f, const float* __restrict__ b1,
    const f16* __restrict__ w2f, const float* __restrict__ b2,
    const float* __restrict__ w3,
    const f16* Xh, const f16* Xl, f16* H1h, f16* H1l, float (*ow)[64][3], int tid)
{
    const int lane = tid & 63;
    const int wid = tid >> 6;       // 0..9
    const int l31 = lane & 31;
    const int l5  = lane >> 5;

    // phase 1: 14 tiles (448 cols), K=32
    for (int rep = 0; rep < 2; ++rep) {
        if (rep == 1 && wid >= 4) break;
        int t = (rep == 0) ? wid : 10 + wid;
        #pragma unroll
        for (int m = 0; m < 2; ++m) {
            f32x16 pm, pc;
            #pragma unroll
            for (int r = 0; r < 16; ++r) { pm[r] = 0.f; pc[r] = 0.f; }
            #pragma unroll
            for (int ks = 0; ks < 2; ++ks) {
                const f16x8 xh = *(const f16x8*)&Xh[(m * 32 + l31) * XPITCH + ks * 16 + l5 * 8];
                const f16x8 xl = *(const f16x8*)&Xl[(m * 32 + l31) * XPITCH + ks * 16 + l5 * 8];
                size_t base = ((size_t)(t * 2 + ks) * 2) * 512 + lane * 8;
                const f16x8 bh = *(const f16x8*)&w1f[base];
                const f16x8 bl = *(const f16x8*)&w1f[base + 512];
                pm = mfma32(xh, bh, pm);
                pc = mfma32(xl, bh, pc);
                pc = mfma32(xh, bl, pc);
            }
            int col = t * 32 + l31;
            float bias = (col < 400) ? b1[col] : 0.f;
            #pragma unroll
            for (int r = 0; r < 16; ++r) {
                int row = m * 32 + (r & 3) + 8 * (r >> 2) + 4 * l5;
                float v = fmaxf(fmaf(pc[r], LO_INV, pm[r]) + bias, 0.f);
                f16 hh, ll; split2f(v, hh, ll);
                H1h[row * AQ_LDH + col] = hh;
                H1l[row * AQ_LDH + col] = ll;
            }
        }
    }
    __syncthreads();

    // phase 2: wave owns n-tile wid (0..9), K=448 (28 ksteps)
    f32x16 am0, ac0, am1, ac1;
    #pragma unroll
    for (int r = 0; r < 16; ++r) { am0[r] = 0.f; ac0[r] = 0.f; am1[r] = 0.f; ac1[r] = 0.f; }
    for (int ks = 0; ks < 28; ++ks) {
        const f16x8 ah0 = *(const f16x8*)&H1h[l31 * AQ_LDH + ks * 16 + l5 * 8];
        const f16x8 al0 = *(const f16x8*)&H1l[l31 * AQ_LDH + ks * 16 + l5 * 8];
        const f16x8 ah1 = *(const f16x8*)&H1h[(32 + l31) * AQ_LDH + ks * 16 + l5 * 8];
        const f16x8 al1 = *(const f16x8*)&H1l[(32 + l31) * AQ_LDH + ks * 16 + l5 * 8];
        size_t base = ((size_t)(wid * 28 + ks) * 2) * 512 + lane * 8;
        const f16x8 bh = *(const f16x8*)&w2f[base];
        const f16x8 bl = *(const f16x8*)&w2f[base + 512];
        am0 = mfma32(ah0, bh, am0);
        ac0 = mfma32(al0, bh, ac0);
        ac0 = mfma32(ah0, bl, ac0);
        am1 = mfma32(ah1, bh, am1);
        ac1 = mfma32(al1, bh, ac1);
        ac1 = mfma32(ah1, bl, ac1);
    }
    #pragma unroll
    for (int r = 0; r < 16; ++r) {
        am0[r] = fmaf(ac0[r], LO_INV, am0[r]);
        am1[r] = fmaf(ac1[r], LO_INV, am1[r]);
    }

    // phase 3
    int col = wid * 32 + l31;
    #pragma unroll
    for (int j = 0; j < NJ; ++j) {
        float p0[16], p1[16];
        #pragma unroll
        for (int r = 0; r < 16; ++r) { p0[r] = 0.f; p1[r] = 0.f; }
        float bias = 0.f, wv = 0.f;
        if (col < 300) { bias = b2[col]; wv = w3[col * NJ + j]; }
        #pragma unroll
        for (int r = 0; r < 16; ++r) {
            p0[r] += fmaxf(am0[r] + bias, 0.f) * wv;
            p1[r] += fmaxf(am1[r] + bias, 0.f) * wv;
        }
        #pragma unroll
        for (int msk = 1; msk < 32; msk <<= 1) {
            #pragma unroll
            for (int r = 0; r < 16; ++r) {
                p0[r] += __shfl_xor(p0[r], msk);
                p1[r] += __shfl_xor(p1[r], msk);
            }
        }
        if (l31 == 0) {
            #pragma unroll
            for (int r = 0; r < 16; ++r) {
                int row = (r & 3) + 8 * (r >> 2) + 4 * l5;
                ow[wid][row][j] = p0[r];
                ow[wid][32 + row][j] = p1[r];
            }
        }
    }
    // caller syncs before reading ow
}

__global__ __launch_bounds__(640, 3) void aq_kernel(
    const float* __restrict__ states, const float* __restrict__ adec,
    const f16* __restrict__ aw1f, const float* __restrict__ ab1,
    const f16* __restrict__ aw2f, const float* __restrict__ ab2,
    const float* __restrict__ aw3, const float* __restrict__ ab3,
    const f16* __restrict__ c1w1f, const float* __restrict__ c1b1,
    const f16* __restrict__ c1w2f, const float* __restrict__ c1b2,
    const float* __restrict__ c1w3, const float* __restrict__ c1b3,
    const f16* __restrict__ c2w1f, const float* __restrict__ c2b1,
    const f16* __restrict__ c2w2f, const float* __restrict__ c2b2,
    const float* __restrict__ c2w3, const float* __restrict__ c2b3,
    float* __restrict__ actions, float* __restrict__ qmin)
{
    __shared__ __align__(16) f16 Xh[64 * XPITCH];
    __shared__ __align__(16) f16 Xl[64 * XPITCH];
    __shared__ __align__(16) f16 H1h[64 * AQ_LDH];
    __shared__ __align__(16) f16 H1l[64 * AQ_LDH];
    __shared__ float ow[10][64][3];
    __shared__ float q1v[64];

    const int tid = threadIdx.x;
    const int rowblk = blockIdx.x * 64;

    // X = [state(11) | a_dec(3) | 0...], pre-split
    for (int idx = tid; idx < 64 * 32; idx += AQ_T) {
        int r = idx >> 5, c = idx & 31;
        int g = rowblk + r;
        float v = 0.f;
        if (c < 11) v = states[(g / 10) * 11 + c];
        else if (c < 14) v = adec[g * 3 + (c - 11)];
        f16 hh, ll; split2f(v, hh, ll);
        Xh[r * XPITCH + c] = hh;
        Xl[r * XPITCH + c] = ll;
    }
    __syncthreads();

    // actor
    mlp_net2<3>(aw1f, ab1, aw2f, ab2, aw3, Xh, Xl, H1h, H1l, ow, tid);
    __syncthreads();
    if (tid < 192) {
        int row = tid / 3, j = tid - row * 3;
        float s = 0.f;
        #pragma unroll
        for (int w = 0; w < 10; ++w) s += ow[w][row][j];
        float da = tanhf(s + ab3[j]);
        float ap = (float)Xh[row * XPITCH + 11 + j]
                 + (float)Xl[row * XPITCH + 11 + j] * LO_INV;
        float act = fminf(fmaxf(0.05f * da + ap, -1.f), 1.f);
        actions[(rowblk + row) * 3 + j] = act;
        f16 hh, ll; split2f(act, hh, ll);
        Xh[row * XPITCH + 11 + j] = hh;
        Xl[row * XPITCH + 11 + j] = ll;
    }
    __syncthreads();

    // q1
    mlp_net2<1>(c1w1f, c1b1, c1w2f, c1b2, c1w3, Xh, Xl, H1h, H1l, ow, tid);
    __syncthreads();
    if (tid < 64) {
        float s = 0.f;
        #pragma unroll
        for (int w = 0; w < 10; ++w) s += ow[w][tid][0];
        q1v[tid] = s + c1b3[0];
    }
    __syncthreads();

    // q2 + min
    mlp_net2<1>(c2w1f, c2b1, c2w2f, c2b2, c2w3, Xh, Xl, H1h, H1l, ow, tid);
    __syncthreads();
    if (tid < 64) {
        float s = 0.f;
        #pragma unroll
        for (int w = 0; w < 10; ++w) s += ow[w][tid][0];
        qmin[rowblk + tid] = fminf(q1v[tid], s + c2b3[0]);
    }
}

// ---------- kernel 3: per-state argmax (first max) + gather ----------
__global__ __launch_bounds__(256) void select_kernel(
    const float* __restrict__ qmin, const float* __restrict__ actions,
    float* __restrict__ out)
{
    int s = blockIdx.x * blockDim.x + threadIdx.x;
    if (s >= 16384) return;
    const float* q = qmin + s * 10;
    int best = 0;
    float bq = q[0];
    #pragma unroll
    for (int i = 1; i < 10; ++i) {
        float v = q[i];
        if (v > bq) { bq = v; best = i; }
    }
    const float* a = actions + (size_t)(s * 10 + best) * 3;
    out[s * 3 + 0] = a[0];
    out[s * 3 + 1] = a[1];
    out[s * 3 + 2] = a[2];
}

extern "C" void kernel_launch(void* const* d_in, const int* in_sizes, int n_in,
                              void* d_out, int out_size, void* d_ws, size_t ws_size,
                              hipStream_t stream)
{
    const float* states = (const float*)d_in[0];
    const float* noise  = (const float*)d_in[1];
    const float* dec_w1 = (const float*)d_in[2];
    const float* dec_b1 = (const float*)d_in[3];
    const float* dec_w2 = (const float*)d_in[4];
    const float* dec_b2 = (const float*)d_in[5];
    const float* dec_w3 = (const float*)d_in[6];
    const float* dec_b3 = (const float*)d_in[7];
    const float* act_w1 = (const float*)d_in[8];
    const float* act_b1 = (const float*)d_in[9];
    const float* act_w2 = (const float*)d_in[10];
    const float* act_b2 = (const float*)d_in[11];
    const float* act_w3 = (const float*)d_in[12];
    const float* act_b3 = (const float*)d_in[13];
    const float* q1_w1 = (const float*)d_in[14];
    const float* q1_b1 = (const float*)d_in[15];
    const float* q1_w2 = (const float*)d_in[16];
    const float* q1_b2 = (const float*)d_in[17];
    const float* q1_w3 = (const float*)d_in[18];
    const float* q1_b3 = (const float*)d_in[19];
    const float* q2_w1 = (const float*)d_in[20];
    const float* q2_b1 = (const float*)d_in[21];
    const float* q2_w2 = (const float*)d_in[22];
    const float* q2_b2 = (const float*)d_in[23];
    const float* q2_w3 = (const float*)d_in[24];
    const float* q2_b3 = (const float*)d_in[25];

    char* base = (char*)d_ws;
    size_t off = 0;
    auto carve = [&](size_t bytes) -> void* {
        void* p = base + off;
        off = (off + bytes + 255) & ~(size_t)255;
        return p;
    };
    f16* w1df = (f16*)carve((size_t)24 * 2 * 1024 * 2);
    f16* w2df = (f16*)carve((size_t)24 * 48 * 1024 * 2);
    f16* aw1f = (f16*)carve((size_t)14 * 2 * 1024 * 2);
    f16* aw2f = (f16*)carve((size_t)10 * 28 * 1024 * 2);
    f16* c1w1f = (f16*)carve((size_t)14 * 2 * 1024 * 2);
    f16* c1w2f = (f16*)carve((size_t)10 * 28 * 1024 * 2);
    f16* c2w1f = (f16*)carve((size_t)14 * 2 * 1024 * 2);
    f16* c2w2f = (f16*)carve((size_t)10 * 28 * 1024 * 2);
    float* adec = (float*)carve((size_t)163840 * 3 * 4);
    float* acts = (float*)carve((size_t)163840 * 3 * 4);
    float* qmn  = (float*)carve((size_t)163840 * 4);
    if (off > ws_size) return;  // workspace too small: bail

    auto prep = [&](const float* W, int K, int N, int ksteps, int ntiles, f16* out) {
        int total = ntiles * ksteps * 512;
        int grid = (total + 255) / 256;
        if (grid > 2048) grid = 2048;
        prep_frag<<<grid, 256, 0, stream>>>(W, K, N, ksteps, ntiles, out);
    };
    prep(dec_w1, 21, 750, 2, 24, w1df);
    prep(dec_w2, 750, 750, 48, 24, w2df);
    prep(act_w1, 14, 400, 2, 14, aw1f);
    prep(act_w2, 400, 300, 28, 10, aw2f);
    prep(q1_w1, 14, 400, 2, 14, c1w1f);
    prep(q1_w2, 400, 300, 28, 10, c1w2f);
    prep(q2_w1, 14, 400, 2, 14, c2w1f);
    prep(q2_w2, 400, 300, 28, 10, c2w2f);

    dec_kernel<<<2560, DEC_T, 0, stream>>>(states, noise,
        w1df, dec_b1, w2df, dec_b2, dec_w3, dec_b3, adec);

    aq_kernel<<<2560, AQ_T, 0, stream>>>(states, adec,
        aw1f, act_b1, aw2f, act_b2, act_w3, act_b3,
        c1w1f, q1_b1, c1w2f, q1_b2, q1_w3, q1_b3,
        c2w1f, q2_b1, c2w2f, q2_b2, q2_w3, q2_b3,
        acts, qmn);

    select_kernel<<<64, 256, 0, stream>>>(qmn, acts, (float*)d_out);
}